// Round 4
// baseline (206.154 us; speedup 1.0000x reference)
//
#include <hip/hip_runtime.h>

// Problem constants (from setup_inputs): B=4, S=8, T=2048, R=256
#define T_N 2048
#define R_N 256
#define SLICES 32                     // B*S
#define NELEM (SLICES * T_N * R_N)    // 16,777,216 per tensor
#define INFV 3.0e38f
#define MIN_BLOCKS 2048               // 2048 x 256 threads, 8 float4/tensor/thread
#define MIN_THREADS (MIN_BLOCKS * 256)
#define LSTR 2056                     // list stride: 2048 + 8 sentinel slots

// CDF layout: FULL word swizzle (R0-verified). Spreads the data-dependent
// corank/merge b32 probes to ~2 lanes/bank (free, m136). Sentinels
// 2048..2055 map to themselves ((e>>5)&31 == 64&31 == 0).
#define XS(e) ((e) ^ (((e) >> 5) & 31))
// RAW layout: quad-preserving swizzle. XORs addr bits [4:2] with bits [7:5];
// bits 0,1 intact -> b128 on 4-aligned quads legal and in-order. NOTE: XQ is
// an involution and 8-element spans are NOT contiguous: XQ(8p+4) = XQ(8p)^4
// (bit 2 is in the XOR mask). The R3 failure was reading the second scan
// quad at rq+4 (hits the INF sentinels at pl=252 -> NaN); correct is rq^4.
// Raw and CDF layouts share the same memory: the scan's psum barrier
// separates the last raw read from the first cdf write.
#define XQ(e) ((e) ^ (((e) >> 3) & 28))

// DPP wave-64 min-reduce step (min is order-insensitive -> bit-safe).
#define DPPMIN(x, ctrl, rmask)                                                 \
    fminf((x), __int_as_float(__builtin_amdgcn_update_dpp(                     \
        0x7f800000, __float_as_int(x), (ctrl), (rmask), 0xf, false)))

// Streaming min, one 16-deep load batch (x then y all in flight).
__global__ __launch_bounds__(256) void kmin(const float* __restrict__ x,
                                            const float* __restrict__ y,
                                            float* __restrict__ partial,
                                            float* __restrict__ out) {
    if (blockIdx.x == 0 && threadIdx.x < 4) out[threadIdx.x] = 0.0f;
    const int g0 = blockIdx.x * 256 + threadIdx.x;   // 0..524287
    const float4* __restrict__ x4 = (const float4*)x;
    const float4* __restrict__ y4 = (const float4*)y;
    float4 va[8], vb[8];
    #pragma unroll
    for (int it = 0; it < 8; ++it) va[it] = x4[g0 + it * MIN_THREADS];
    #pragma unroll
    for (int it = 0; it < 8; ++it) vb[it] = y4[g0 + it * MIN_THREADS];
    float m0 = INFV, m1 = INFV;
    #pragma unroll
    for (int it = 0; it < 8; ++it)
        m0 = fminf(m0, fminf(fminf(va[it].x, va[it].y), fminf(va[it].z, va[it].w)));
    #pragma unroll
    for (int it = 0; it < 8; ++it)
        m1 = fminf(m1, fminf(fminf(vb[it].x, vb[it].y), fminf(vb[it].z, vb[it].w)));
    float m = fminf(m0, m1);
    #pragma unroll
    for (int off = 32; off; off >>= 1) m = fminf(m, __shfl_down(m, off));
    __shared__ float sm[4];
    if ((threadIdx.x & 63) == 0) sm[threadIdx.x >> 6] = m;
    __syncthreads();
    if (threadIdx.x == 0)
        partial[blockIdx.x] = fminf(fminf(sm[0], sm[1]), fminf(sm[2], sm[3]));
}

// 1024-thread block = 4 problems, 4 waves/problem (verified structure).
// Split LDS layout (XQ raw / XS cdf): b128 staging + b128 scan reads,
// full-swizzle b32 cdf for the random corank/merge probes, float4 reads of
// red16/psum/pacc. All order-sensitive arithmetic bit-identical to R2.
__global__ __launch_bounds__(1024, 8) void kmain(const float* __restrict__ x,
                                                 const float* __restrict__ y,
                                                 const float* __restrict__ partial,
                                                 float* __restrict__ out) {
    __shared__ __align__(16) float L[8 * LSTR];  // problem p: U at (2p)*LSTR, V at (2p+1)*LSTR
    __shared__ __align__(16) float red16[16];
    __shared__ __align__(16) float psum[4][2][4];  // [problem][list][wave-chunk]
    __shared__ __align__(16) float pacc[4][4];     // [problem][wave]

    const int tid = threadIdx.x;
    const int w = tid >> 6;           // wave 0..15
    const int lane = tid & 63;

    // ---- XCD-aware remap: 4 blocks sharing a 64B global line -> same XCD ----
    const int blk = blockIdx.x;
    const int xcd = blk & 7;
    const int k2 = blk >> 3;
    const int sub = k2 & 3;
    const int rest = k2 >> 2;
    const int rt = (((rest & 1) << 3) + xcd) * 4 + sub;   // 0..63
    const int bs = rest >> 1;                              // 0..31
    const size_t base = (size_t)bs * (T_N * R_N) + (size_t)(rt * 4);

    // ---- staging loads EARLY (independent of sh): by-tensor split ----
    // waves 0-7 stage x, waves 8-15 stage y; 4 consecutive rows/thread.
    const int st = tid & 511;
    const int r0 = st << 2;                        // rows r0..r0+3
    const int lb = tid >> 9;                       // 0 = x-lists, 1 = y-lists
    const float* __restrict__ src = (lb == 0) ? x : y;
    const float4 g0v = *(const float4*)(src + base + (size_t)(r0 + 0) * R_N);
    const float4 g1v = *(const float4*)(src + base + (size_t)(r0 + 1) * R_N);
    const float4 g2v = *(const float4*)(src + base + (size_t)(r0 + 2) * R_N);
    const float4 g3v = *(const float4*)(src + base + (size_t)(r0 + 3) * R_N);

    // ---- phase 0: global min (partial[2048]) via DPP ----
    {
        float m = fminf(partial[tid], partial[tid + 1024]);
        m = DPPMIN(m, 0x111, 0xf);    // row_shr:1
        m = DPPMIN(m, 0x112, 0xf);    // row_shr:2
        m = DPPMIN(m, 0x114, 0xf);    // row_shr:4
        m = DPPMIN(m, 0x118, 0xf);    // row_shr:8
        m = DPPMIN(m, 0x142, 0xa);    // row_bcast:15 -> rows 1,3
        m = DPPMIN(m, 0x143, 0xc);    // row_bcast:31 -> rows 2,3
        if (lane == 63) red16[w] = m;
    }
    // ---- sentinels: logical 2048..2055 (identity in XS layout) = INF ----
    if (tid < 64) L[(tid >> 3) * LSTR + T_N + (tid & 7)] = INFV;
    __syncthreads();
    const float4 q0 = *(const float4*)&red16[0];
    const float4 q1 = *(const float4*)&red16[4];
    const float4 q2 = *(const float4*)&red16[8];
    const float4 q3 = *(const float4*)&red16[12];
    const float mn =
        fminf(fminf(fminf(fminf(q0.x, q0.y), fminf(q0.z, q0.w)),
                    fminf(fminf(q1.x, q1.y), fminf(q1.z, q1.w))),
              fminf(fminf(fminf(q2.x, q2.y), fminf(q2.z, q2.w)),
                    fminf(fminf(q3.x, q3.y), fminf(q3.z, q3.w))));
    const float sh = 1.1f * fminf(mn, 0.0f);

    // ---- staging: b128 quad writes into XQ raw layout ----
    {
        const int wq = r0 ^ ((r0 >> 3) & 28);      // XQ(r0); quad-preserved
        *(float4*)&L[(0 + lb) * LSTR + wq] =
            make_float4(g0v.x - sh, g1v.x - sh, g2v.x - sh, g3v.x - sh);
        *(float4*)&L[(2 + lb) * LSTR + wq] =
            make_float4(g0v.y - sh, g1v.y - sh, g2v.y - sh, g3v.y - sh);
        *(float4*)&L[(4 + lb) * LSTR + wq] =
            make_float4(g0v.z - sh, g1v.z - sh, g2v.z - sh, g3v.z - sh);
        *(float4*)&L[(6 + lb) * LSTR + wq] =
            make_float4(g0v.w - sh, g1v.w - sh, g2v.w - sh, g3v.w - sh);
    }
    __syncthreads();

    const int p  = w >> 2;            // problem 0..3
    const int wl = w & 3;             // wave within problem
    const int pl = (wl << 6) | lane;  // problem-lane 0..255
    float* __restrict__ cu = &L[(2 * p) * LSTR];
    float* __restrict__ cv = &L[(2 * p + 1) * LSTR];

    // ---- scan: lane owns logical [8*pl, 8*pl+8) ----
    // reads from XQ raw layout: quad XQ(8pl) = rq, quad XQ(8pl+4) = rq^4
    // (NOT rq+4 -- bit 2 is in the XOR mask). Writes to XS cdf layout (b32).
    {
        const int rq = (8 * pl) ^ (pl & 28);       // XQ(8*pl)
        float uu[8], vv8[8];
        {
            const float4 t0 = *(const float4*)&cu[rq];
            const float4 t1 = *(const float4*)&cu[rq ^ 4];
            uu[0] = t0.x; uu[1] = t0.y; uu[2] = t0.z; uu[3] = t0.w;
            uu[4] = t1.x; uu[5] = t1.y; uu[6] = t1.z; uu[7] = t1.w;
        }
        float su = 0.f, sv = 0.f;
        #pragma unroll
        for (int k = 0; k < 8; ++k) su += uu[k];
        {
            const float4 t0 = *(const float4*)&cv[rq];
            const float4 t1 = *(const float4*)&cv[rq ^ 4];
            vv8[0] = t0.x; vv8[1] = t0.y; vv8[2] = t0.z; vv8[3] = t0.w;
            vv8[4] = t1.x; vv8[5] = t1.y; vv8[6] = t1.z; vv8[7] = t1.w;
        }
        #pragma unroll
        for (int k = 0; k < 8; ++k) sv += vv8[k];
        float iu = su, iv = sv;
        #pragma unroll
        for (int off = 1; off < 64; off <<= 1) {
            const float a = __shfl_up(iu, off);
            const float b = __shfl_up(iv, off);
            if (lane >= off) { iu += a; iv += b; }
        }
        if (lane == 63) { psum[p][0][wl] = iu; psum[p][1][wl] = iv; }
        __syncthreads();
        const float4 pu4 = *(const float4*)&psum[p][0][0];
        const float4 pv4 = *(const float4*)&psum[p][1][0];
        const float puA[4] = {pu4.x, pu4.y, pu4.z, pu4.w};
        const float pvA[4] = {pv4.x, pv4.y, pv4.z, pv4.w};
        float prefU = 0.f, totU = 0.f, prefV = 0.f, totV = 0.f;
        #pragma unroll
        for (int k = 0; k < 4; ++k) {
            totU += puA[k]; totV += pvA[k];
            if (k < wl) { prefU += puA[k]; prefV += pvA[k]; }
        }
        const float invU = 1.0f / totU, invV = 1.0f / totV;
        float ru = prefU + (iu - su);
        float rv = prefV + (iv - sv);
        const int cm = (pl >> 2) & 31;             // XS mask, hoisted
        #pragma unroll
        for (int k = 0; k < 8; ++k) { ru += uu[k];  cu[(8 * pl + k) ^ cm] = ru * invU; }
        #pragma unroll
        for (int k = 0; k < 8; ++k) { rv += vv8[k]; cv[(8 * pl + k) ^ cm] = rv * invV; }
    }
    __syncthreads();

    // ---- co-rank partition: lane handles merged window [16*pl, 16*pl+16) ----
    const int d = pl << 4;
    int i = 0, j = 0;
    if (d > 0) {
        int lo = (d > T_N) ? (d - T_N) : 0;
        int hi = (d < T_N) ? d : T_N;
        while (lo < hi) {
            const int mid = (lo + hi) >> 1;
            if (cu[XS(mid)] <= cv[XS(d - mid - 1)]) lo = mid + 1; else hi = mid;
        }
        i = lo; j = d - lo;
    }
    float qprev = 0.0f;
    if (d > 0) {
        const float pa_ = (i > 0) ? cu[XS(i - 1)] : -INFV;
        const float pb_ = (j > 0) ? cv[XS(j - 1)] : -INFV;
        qprev = fmaxf(pa_, pb_);
    }

    // ---- merge: 16 steps, refill only the advanced list, sentinel-direct ----
    float uv = cu[XS(i)];
    float vv = cv[XS(j)];
    float acc = 0.0f;
    #pragma unroll
    for (int s = 0; s < 16; ++s) {
        const bool take = (uv <= vv);
        const float q = fminf(uv, vv);
        const float dd = (float)(min(i, T_N - 1) - min(j, T_N - 1));
        acc += (q - qprev) * dd * dd;
        qprev = q;
        i += take ? 1 : 0;
        j += take ? 0 : 1;
        if (s < 15) {
            const int ni = take ? i : j;           // advanced index (<= 2048)
            const float* bp = take ? cu : cv;
            const float r = bp[XS(ni)];
            uv = take ? r : uv;
            vv = take ? vv : r;
        }
    }

    // ---- reduce: wave -> LDS -> one atomic per block (order preserved) ----
    #pragma unroll
    for (int off = 32; off; off >>= 1) acc += __shfl_down(acc, off);
    if (lane == 0) pacc[p][wl] = acc;
    __syncthreads();
    if (tid == 0) {
        float r = 0.f;
        #pragma unroll
        for (int pp = 0; pp < 4; ++pp) {
            const float4 pa4 = *(const float4*)&pacc[pp][0];
            r += (pa4.x + pa4.y) + (pa4.z + pa4.w);
        }
        atomicAdd(&out[bs >> 3], r * (1.0f / ((float)T_N * (float)T_N)));
    }
}

extern "C" void kernel_launch(void* const* d_in, const int* in_sizes, int n_in,
                              void* d_out, int out_size, void* d_ws, size_t ws_size,
                              hipStream_t stream) {
    const float* x = (const float*)d_in[0];
    const float* y = (const float*)d_in[1];
    float* out = (float*)d_out;
    float* partial = (float*)d_ws;   // MIN_BLOCKS floats (8 KiB)

    kmin<<<MIN_BLOCKS, 256, 0, stream>>>(x, y, partial, out);
    kmain<<<SLICES * 64, 1024, 0, stream>>>(x, y, partial, out);
}